// Round 1
// baseline (5360.220 us; speedup 1.0000x reference)
//
#include <hip/hip_runtime.h>
#include <stdint.h>

typedef __attribute__((ext_vector_type(8)))  short   short8;
typedef __attribute__((ext_vector_type(8)))  unsigned short ushort8;
typedef __attribute__((ext_vector_type(8)))  __bf16  bf16x8;
typedef __attribute__((ext_vector_type(4)))  float   floatx4;
typedef __attribute__((ext_vector_type(4)))  unsigned short ushort4v;

#define AS1 __attribute__((address_space(1)))
#define AS3 __attribute__((address_space(3)))

__device__ __forceinline__ unsigned short f2bf(float f) {
  unsigned u = __builtin_bit_cast(unsigned, f);
  u = (u + 0x7FFFu + ((u >> 16) & 1u)) >> 16;   // RNE
  return (unsigned short)u;
}
__device__ __forceinline__ float bf2f(unsigned short h) {
  unsigned u = ((unsigned)h) << 16;
  return __builtin_bit_cast(float, u);
}

// ---------------- f32 -> bf16 convert (n multiple of 1024) ----------------
__global__ __launch_bounds__(256) void convert_bf16(const float* __restrict__ src,
                                                    unsigned short* __restrict__ dst,
                                                    int n) {
  int i = (blockIdx.x * 256 + threadIdx.x) * 4;
  if (i >= n) return;
  float4 v = *(const float4*)(src + i);
  ushort4v o;
  o.x = f2bf(v.x); o.y = f2bf(v.y); o.z = f2bf(v.z); o.w = f2bf(v.w);
  *(ushort4v*)(dst + i) = o;
}

// ---------------- int64-vs-int32 id layout detection ----------------
// If ids arrived as int64, every odd 32-bit word is 0 (values < 2^31).
// For random int32 ids in [0,32000) the OR over 2048 odd words is ~surely nonzero.
__global__ __launch_bounds__(256) void detect_i64(const int* __restrict__ idbuf,
                                                  int* __restrict__ flag) {
  int v = 0;
  for (int i = threadIdx.x; i < 2048; i += 256) v |= idbuf[2 * i + 1];
  if (v != 0) atomicOr(flag, 1);
}

// ---------------- gather rows of emb -> bf16 x ----------------
__global__ __launch_bounds__(256) void gather_embed(const int* __restrict__ ids,
                                                    const float* __restrict__ emb,
                                                    unsigned short* __restrict__ xbf,
                                                    const int* __restrict__ flag) {
  int i = blockIdx.x;                      // 0..4095 (b*256+s)
  int row = (*flag != 0) ? ids[i] : ids[2 * i];   // int32 vs int64 layout
  const float* src = emb + (size_t)row * 1024 + threadIdx.x * 4;
  float4 v = *(const float4*)src;
  ushort4v o;
  o.x = f2bf(v.x); o.y = f2bf(v.y); o.z = f2bf(v.z); o.w = f2bf(v.w);
  *(ushort4v*)(xbf + (size_t)i * 1024 + threadIdx.x * 4) = o;
}

// ---------------- bf16 GEMM  C[M,N] = A[M,K] * B[N,K]^T  (f32 out) ----------------
// 128x128 tile, BK=64, 4 waves (2x2), 4x4 16x16x32 MFMA fragments per wave.
// M,N multiples of 128; K multiple of 64; grid = (M/128)*(N/128), divisible by 8.
__global__ __launch_bounds__(256) void gemm_bt(const unsigned short* __restrict__ A,
                                               const unsigned short* __restrict__ B,
                                               float* __restrict__ C,
                                               int M, int N, int K) {
  __shared__ unsigned short lA[128 * 64];
  __shared__ unsigned short lB[128 * 64];
  const int nwg  = gridDim.x;
  const int wgid = blockIdx.x;
  const int q    = nwg >> 3;                       // XCD-aware swizzle (nwg % 8 == 0)
  const int swz  = (wgid & 7) * q + (wgid >> 3);
  const int ntx  = N >> 7;
  const int bx   = swz % ntx;
  const int by   = swz / ntx;
  const int tid  = threadIdx.x;
  const int lane = tid & 63;
  const int w    = tid >> 6;
  const int wr   = w >> 1, wc = w & 1;

  floatx4 acc[4][4];
#pragma unroll
  for (int m = 0; m < 4; ++m)
#pragma unroll
    for (int n = 0; n < 4; ++n) acc[m][n] = (floatx4){0.f, 0.f, 0.f, 0.f};

  const size_t rowA0 = (size_t)by * 128;
  const size_t colB0 = (size_t)bx * 128;

  for (int k0 = 0; k0 < K; k0 += 64) {
    // stage 128x64 bf16 tiles of A and B into LDS (linear layout, 16B/lane)
#pragma unroll
    for (int p = 0; p < 4; ++p) {
      int cc = p * 256 + tid;       // 16B chunk id, 0..1023
      int r  = cc >> 3;             // tile row 0..127
      int c8 = cc & 7;              // 16B chunk within row
      const unsigned short* srcA = A + (rowA0 + r) * K + k0 + c8 * 8;
      const unsigned short* srcB = B + (colB0 + r) * K + k0 + c8 * 8;
      __builtin_amdgcn_global_load_lds((const AS1 unsigned int*)srcA,
                                       (AS3 unsigned int*)&lA[cc * 8], 16, 0, 0);
      __builtin_amdgcn_global_load_lds((const AS1 unsigned int*)srcB,
                                       (AS3 unsigned int*)&lB[cc * 8], 16, 0, 0);
    }
    __syncthreads();
#pragma unroll
    for (int kk = 0; kk < 2; ++kk) {
      const int kofs = kk * 32 + (lane >> 4) * 8;
      bf16x8 af[4], bfv[4];
#pragma unroll
      for (int m = 0; m < 4; ++m) {
        int r = wr * 64 + m * 16 + (lane & 15);
        af[m] = *(const bf16x8*)&lA[r * 64 + kofs];
      }
#pragma unroll
      for (int n = 0; n < 4; ++n) {
        int r = wc * 64 + n * 16 + (lane & 15);
        bfv[n] = *(const bf16x8*)&lB[r * 64 + kofs];
      }
#pragma unroll
      for (int m = 0; m < 4; ++m)
#pragma unroll
        for (int n = 0; n < 4; ++n)
          acc[m][n] = __builtin_amdgcn_mfma_f32_16x16x32_bf16(af[m], bfv[n], acc[m][n], 0, 0, 0);
    }
    __syncthreads();
  }

  // epilogue: C/D layout col=lane&15, row=(lane>>4)*4+j
#pragma unroll
  for (int m = 0; m < 4; ++m) {
#pragma unroll
    for (int j = 0; j < 4; ++j) {
      size_t row = rowA0 + wr * 64 + m * 16 + ((lane >> 4) * 4 + j);
      float* crow = C + row * (size_t)N + colB0 + wc * 64 + (lane & 15);
#pragma unroll
      for (int n = 0; n < 4; ++n) crow[n * 16] = acc[m][n][j];
    }
  }
}

// ---------------- recurrence: h_t = tanh(xin_t + h_{t-1} @ w_hh^T) ----------------
// 256 WGs = 16 batches x 16 slices of 64 output rows. 1024 threads/WG.
// Thread (o=tid&63, kc=tid>>6) holds w_hh[slice*64+o][kc*64 .. +64) as f32 in regs.
// Per-batch barrier: device-scope atomic counter, release/acquire.
__global__ __launch_bounds__(1024) void rnn_step_all(const float* __restrict__ xin,
                                                     const unsigned short* __restrict__ whh_bf,
                                                     float* __restrict__ hs,
                                                     unsigned short* __restrict__ hs_bf,
                                                     unsigned int* __restrict__ cnt) {
  const int b     = blockIdx.x >> 4;
  const int slice = blockIdx.x & 15;
  const int tid   = threadIdx.x;
  const int o     = tid & 63;
  const int kc    = tid >> 6;

  __shared__ __align__(16) float hl[1024];
  __shared__ float red[1024];

  float wf[64];
  {
    const unsigned short* wrow = whh_bf + (size_t)(slice * 64 + o) * 1024 + kc * 64;
#pragma unroll
    for (int j = 0; j < 8; ++j) {
      ushort8 wv = *(const ushort8*)(wrow + j * 8);
#pragma unroll
      for (int e = 0; e < 8; ++e) wf[j * 8 + e] = bf2f(wv[e]);
    }
  }

  const size_t bbase = (size_t)b * 256 * 1024;

  for (int t = 0; t < 256; ++t) {
    hl[tid] = (t == 0) ? 0.0f : hs[bbase + (size_t)(t - 1) * 1024 + tid];
    __syncthreads();

    float sum = 0.0f;
#pragma unroll
    for (int j4 = 0; j4 < 16; ++j4) {
      float4 hv = *(const float4*)&hl[kc * 64 + j4 * 4];
      sum += wf[j4 * 4 + 0] * hv.x + wf[j4 * 4 + 1] * hv.y +
             wf[j4 * 4 + 2] * hv.z + wf[j4 * 4 + 3] * hv.w;
    }
    red[tid] = sum;          // red[kc*64+o] == red[tid]
    __syncthreads();

    if (tid < 64) {
      float s = xin[bbase + (size_t)t * 1024 + slice * 64 + tid];
#pragma unroll
      for (int k2 = 0; k2 < 16; ++k2) s += red[k2 * 64 + tid];
      float hv   = tanhf(s);
      size_t idx = bbase + (size_t)t * 1024 + slice * 64 + tid;
      hs[idx]    = hv;
      hs_bf[idx] = f2bf(hv);
    }
    __syncthreads();

    if (tid == 0) {
      __hip_atomic_fetch_add(&cnt[b], 1u, __ATOMIC_RELEASE, __HIP_MEMORY_SCOPE_AGENT);
      const unsigned target = 16u * (unsigned)(t + 1);
      while (__hip_atomic_load(&cnt[b], __ATOMIC_ACQUIRE, __HIP_MEMORY_SCOPE_AGENT) < target)
        __builtin_amdgcn_s_sleep(1);
    }
    __syncthreads();
  }
}

// ---------------- host launch ----------------
extern "C" void kernel_launch(void* const* d_in, const int* in_sizes, int n_in,
                              void* d_out, int out_size, void* d_ws, size_t ws_size,
                              hipStream_t stream) {
  const int*   ids  = (const int*)d_in[0];     // [16,256]
  const float* emb  = (const float*)d_in[1];   // [32000,1024]
  const float* w_hx = (const float*)d_in[2];   // [1024,1024]
  const float* w_hh = (const float*)d_in[3];   // [1024,1024]
  const float* w_yh = (const float*)d_in[4];   // [32000,1024]
  float*       out  = (float*)d_out;           // [16,256,32000]

  const int B = 16, S = 256, H = 1024, V = 32000;
  const int BS = B * S;

  char*  ws  = (char*)d_ws;
  size_t off = 0;
  auto alloc = [&](size_t bytes) {
    size_t cur = off;
    off += (bytes + 255) & ~(size_t)255;
    return (void*)(ws + cur);
  };

  unsigned short* whx_bf = (unsigned short*)alloc((size_t)H * H * 2);
  unsigned short* whh_bf = (unsigned short*)alloc((size_t)H * H * 2);
  unsigned short* wyh_bf = (unsigned short*)alloc((size_t)V * H * 2);
  unsigned short* x_bf   = (unsigned short*)alloc((size_t)BS * H * 2);
  float*          xin    = (float*)alloc((size_t)BS * H * 4);
  float*          hs     = (float*)alloc((size_t)BS * H * 4);
  unsigned short* hs_bf  = (unsigned short*)alloc((size_t)BS * H * 2);
  unsigned int*   cnt    = (unsigned int*)alloc(256);   // [16] counters + flag
  int*            flag   = (int*)(cnt + 32);

  hipMemsetAsync(cnt, 0, 256, stream);   // zero counters + detection flag each call

  detect_i64<<<dim3(1), dim3(256), 0, stream>>>(ids, flag);
  convert_bf16<<<dim3((H * H) / 1024), dim3(256), 0, stream>>>(w_hx, whx_bf, H * H);
  convert_bf16<<<dim3((H * H) / 1024), dim3(256), 0, stream>>>(w_hh, whh_bf, H * H);
  convert_bf16<<<dim3((V * H) / 1024), dim3(256), 0, stream>>>(w_yh, wyh_bf, V * H);
  gather_embed<<<dim3(BS), dim3(256), 0, stream>>>(ids, emb, x_bf, flag);

  // xin = x @ w_hx^T : M=4096, N=1024, K=1024 -> 256 WGs
  gemm_bt<<<dim3((BS / 128) * (H / 128)), dim3(256), 0, stream>>>(x_bf, whx_bf, xin, BS, H, H);

  // sequential recurrence (persistent, per-batch atomic barriers)
  rnn_step_all<<<dim3(256), dim3(1024), 0, stream>>>(xin, whh_bf, hs, hs_bf, cnt);

  // logits = hs @ w_yh^T : M=4096, N=32000, K=1024 -> 8000 WGs
  gemm_bt<<<dim3((BS / 128) * (V / 128)), dim3(256), 0, stream>>>(hs_bf, wyh_bf, out, BS, V, H);
}

// Round 2
// 1069.881 us; speedup vs baseline: 5.0101x; 5.0101x over previous
//
#include <hip/hip_runtime.h>
#include <stdint.h>

typedef __attribute__((ext_vector_type(8)))  short   short8;
typedef __attribute__((ext_vector_type(8)))  unsigned short ushort8;
typedef __attribute__((ext_vector_type(8)))  __bf16  bf16x8;
typedef __attribute__((ext_vector_type(4)))  float   floatx4;
typedef __attribute__((ext_vector_type(4)))  unsigned short ushort4v;

#define AS1 __attribute__((address_space(1)))
#define AS3 __attribute__((address_space(3)))

__device__ __forceinline__ unsigned short f2bf(float f) {
  unsigned u = __builtin_bit_cast(unsigned, f);
  u = (u + 0x7FFFu + ((u >> 16) & 1u)) >> 16;   // RNE
  return (unsigned short)u;
}
__device__ __forceinline__ float bf2f(unsigned short h) {
  unsigned u = ((unsigned)h) << 16;
  return __builtin_bit_cast(float, u);
}

// ---------------- f32 -> bf16 convert (n multiple of 1024) ----------------
__global__ __launch_bounds__(256) void convert_bf16(const float* __restrict__ src,
                                                    unsigned short* __restrict__ dst,
                                                    int n) {
  int i = (blockIdx.x * 256 + threadIdx.x) * 4;
  if (i >= n) return;
  float4 v = *(const float4*)(src + i);
  ushort4v o;
  o.x = f2bf(v.x); o.y = f2bf(v.y); o.z = f2bf(v.z); o.w = f2bf(v.w);
  *(ushort4v*)(dst + i) = o;
}

// ---------------- int64-vs-int32 id layout detection ----------------
__global__ __launch_bounds__(256) void detect_i64(const int* __restrict__ idbuf,
                                                  int* __restrict__ flag) {
  int v = 0;
  for (int i = threadIdx.x; i < 2048; i += 256) v |= idbuf[2 * i + 1];
  if (v != 0) atomicOr(flag, 1);
}

// ---------------- gather rows of emb -> bf16 x ----------------
__global__ __launch_bounds__(256) void gather_embed(const int* __restrict__ ids,
                                                    const float* __restrict__ emb,
                                                    unsigned short* __restrict__ xbf,
                                                    const int* __restrict__ flag) {
  int i = blockIdx.x;                      // 0..4095 (b*256+s)
  int row = (*flag != 0) ? ids[i] : ids[2 * i];   // int32 vs int64 layout
  const float* src = emb + (size_t)row * 1024 + threadIdx.x * 4;
  float4 v = *(const float4*)src;
  ushort4v o;
  o.x = f2bf(v.x); o.y = f2bf(v.y); o.z = f2bf(v.z); o.w = f2bf(v.w);
  *(ushort4v*)(xbf + (size_t)i * 1024 + threadIdx.x * 4) = o;
}

// ---------------- bf16 GEMM  C[M,N] = A[M,K] * B[N,K]^T  (f32 out) ----------------
__global__ __launch_bounds__(256) void gemm_bt(const unsigned short* __restrict__ A,
                                               const unsigned short* __restrict__ B,
                                               float* __restrict__ C,
                                               int M, int N, int K) {
  __shared__ unsigned short lA[128 * 64];
  __shared__ unsigned short lB[128 * 64];
  const int nwg  = gridDim.x;
  const int wgid = blockIdx.x;
  const int q    = nwg >> 3;                       // XCD-aware swizzle (nwg % 8 == 0)
  const int swz  = (wgid & 7) * q + (wgid >> 3);
  const int ntx  = N >> 7;
  const int bx   = swz % ntx;
  const int by   = swz / ntx;
  const int tid  = threadIdx.x;
  const int lane = tid & 63;
  const int w    = tid >> 6;
  const int wr   = w >> 1, wc = w & 1;

  floatx4 acc[4][4];
#pragma unroll
  for (int m = 0; m < 4; ++m)
#pragma unroll
    for (int n = 0; n < 4; ++n) acc[m][n] = (floatx4){0.f, 0.f, 0.f, 0.f};

  const size_t rowA0 = (size_t)by * 128;
  const size_t colB0 = (size_t)bx * 128;

  for (int k0 = 0; k0 < K; k0 += 64) {
#pragma unroll
    for (int p = 0; p < 4; ++p) {
      int cc = p * 256 + tid;       // 16B chunk id, 0..1023
      int r  = cc >> 3;             // tile row 0..127
      int c8 = cc & 7;              // 16B chunk within row
      const unsigned short* srcA = A + (rowA0 + r) * K + k0 + c8 * 8;
      const unsigned short* srcB = B + (colB0 + r) * K + k0 + c8 * 8;
      __builtin_amdgcn_global_load_lds((const AS1 unsigned int*)srcA,
                                       (AS3 unsigned int*)&lA[cc * 8], 16, 0, 0);
      __builtin_amdgcn_global_load_lds((const AS1 unsigned int*)srcB,
                                       (AS3 unsigned int*)&lB[cc * 8], 16, 0, 0);
    }
    __syncthreads();
#pragma unroll
    for (int kk = 0; kk < 2; ++kk) {
      const int kofs = kk * 32 + (lane >> 4) * 8;
      bf16x8 af[4], bfv[4];
#pragma unroll
      for (int m = 0; m < 4; ++m) {
        int r = wr * 64 + m * 16 + (lane & 15);
        af[m] = *(const bf16x8*)&lA[r * 64 + kofs];
      }
#pragma unroll
      for (int n = 0; n < 4; ++n) {
        int r = wc * 64 + n * 16 + (lane & 15);
        bfv[n] = *(const bf16x8*)&lB[r * 64 + kofs];
      }
#pragma unroll
      for (int m = 0; m < 4; ++m)
#pragma unroll
        for (int n = 0; n < 4; ++n)
          acc[m][n] = __builtin_amdgcn_mfma_f32_16x16x32_bf16(af[m], bfv[n], acc[m][n], 0, 0, 0);
    }
    __syncthreads();
  }

#pragma unroll
  for (int m = 0; m < 4; ++m) {
#pragma unroll
    for (int j = 0; j < 4; ++j) {
      size_t row = rowA0 + wr * 64 + m * 16 + ((lane >> 4) * 4 + j);
      float* crow = C + row * (size_t)N + colB0 + wc * 64 + (lane & 15);
#pragma unroll
      for (int n = 0; n < 4; ++n) crow[n * 16] = acc[m][n][j];
    }
  }
}

// ---------------- recurrence: h_t = tanh(xin_t + h_{t-1} @ w_hh^T) ----------------
// 256 WGs = 16 batches x 16 slices of 64 output rows. 1024 threads/WG.
// Thread (o=tid&63, kc=tid>>6) holds w_hh[slice*64+o][kc*64 .. +64) as f32 in regs.
// Sync protocol (per batch): single-writer flags, device-coherent data stores,
// manual ordering (vmcnt drain between data stores and flag store). Wave kc of
// a consumer WG only needs producer slice kc's chunk -> per-wave poll+gather.
__global__ __launch_bounds__(1024) void rnn_step_all(const float* __restrict__ xin,
                                                     const unsigned short* __restrict__ whh_bf,
                                                     float* __restrict__ hs,
                                                     unsigned short* __restrict__ hs_bf,
                                                     unsigned int* __restrict__ flags) {
  const int b     = blockIdx.x >> 4;
  const int slice = blockIdx.x & 15;
  const int tid   = threadIdx.x;
  const int o     = tid & 63;     // lane within wave
  const int kc    = tid >> 6;     // wave id == k-chunk == source slice

  __shared__ __align__(16) float hl[1024];
  __shared__ float red[1024];

  float wf[64];
  {
    const unsigned short* wrow = whh_bf + (size_t)(slice * 64 + o) * 1024 + kc * 64;
#pragma unroll
    for (int j = 0; j < 8; ++j) {
      ushort8 wv = *(const ushort8*)(wrow + j * 8);
#pragma unroll
      for (int e = 0; e < 8; ++e) wf[j * 8 + e] = bf2f(wv[e]);
    }
  }

  const size_t bbase = (size_t)b * 256 * 1024;
  unsigned int* bflags = flags + b * 64;   // 256B stride per batch

  for (int t = 0; t < 256; ++t) {
    // --- gather h_{t-1}[kc*64 .. +64) : produced by slice kc of this batch ---
    if (t == 0) {
      hl[tid] = 0.0f;
    } else {
      // wave kc polls only flag[kc] (uniform address -> single broadcast load)
      while (__hip_atomic_load(&bflags[kc], __ATOMIC_RELAXED,
                               __HIP_MEMORY_SCOPE_AGENT) < (unsigned)t) { }
      asm volatile("" ::: "memory");   // no compiler reordering of the data loads
      hl[tid] = __hip_atomic_load(&hs[bbase + (size_t)(t - 1) * 1024 + tid],
                                  __ATOMIC_RELAXED, __HIP_MEMORY_SCOPE_AGENT);
    }
    // wave kc reads back only its own chunk -> no cross-wave barrier needed
    float sum = 0.0f;
#pragma unroll
    for (int j4 = 0; j4 < 16; ++j4) {
      float4 hv = *(const float4*)&hl[kc * 64 + j4 * 4];
      sum += wf[j4 * 4 + 0] * hv.x + wf[j4 * 4 + 1] * hv.y +
             wf[j4 * 4 + 2] * hv.z + wf[j4 * 4 + 3] * hv.w;
    }
    red[tid] = sum;
    float s = 0.0f;
    if (tid < 64) s = xin[bbase + (size_t)t * 1024 + slice * 64 + tid];  // issue early
    __syncthreads();                       // red[] ready

    if (tid < 64) {
#pragma unroll
      for (int k2 = 0; k2 < 16; ++k2) s += red[k2 * 64 + tid];
      float hv   = tanhf(s);
      size_t idx = bbase + (size_t)t * 1024 + slice * 64 + tid;
      // device-coherent data store (bypasses L2; at coherence point when vmcnt==0)
      __hip_atomic_store(&hs[idx], hv, __ATOMIC_RELAXED, __HIP_MEMORY_SCOPE_AGENT);
      hs_bf[idx] = f2bf(hv);               // plain store; consumed after kernel end
      asm volatile("s_waitcnt vmcnt(0)" ::: "memory");   // data at coherence point
      if (tid == 0)
        __hip_atomic_store(&bflags[slice], (unsigned)(t + 1),
                           __ATOMIC_RELAXED, __HIP_MEMORY_SCOPE_AGENT);
    }
    __syncthreads();                       // protect red[] reuse next iteration
  }
}

// ---------------- host launch ----------------
extern "C" void kernel_launch(void* const* d_in, const int* in_sizes, int n_in,
                              void* d_out, int out_size, void* d_ws, size_t ws_size,
                              hipStream_t stream) {
  const int*   ids  = (const int*)d_in[0];     // [16,256]
  const float* emb  = (const float*)d_in[1];   // [32000,1024]
  const float* w_hx = (const float*)d_in[2];   // [1024,1024]
  const float* w_hh = (const float*)d_in[3];   // [1024,1024]
  const float* w_yh = (const float*)d_in[4];   // [32000,1024]
  float*       out  = (float*)d_out;           // [16,256,32000]

  const int B = 16, S = 256, H = 1024, V = 32000;
  const int BS = B * S;

  char*  ws  = (char*)d_ws;
  size_t off = 0;
  auto alloc = [&](size_t bytes) {
    size_t cur = off;
    off += (bytes + 255) & ~(size_t)255;
    return (void*)(ws + cur);
  };

  unsigned short* whx_bf = (unsigned short*)alloc((size_t)H * H * 2);
  unsigned short* whh_bf = (unsigned short*)alloc((size_t)H * H * 2);
  unsigned short* wyh_bf = (unsigned short*)alloc((size_t)V * H * 2);
  unsigned short* x_bf   = (unsigned short*)alloc((size_t)BS * H * 2);
  float*          xin    = (float*)alloc((size_t)BS * H * 4);
  float*          hs     = (float*)alloc((size_t)BS * H * 4);
  unsigned short* hs_bf  = (unsigned short*)alloc((size_t)BS * H * 2);
  unsigned int*   flags  = (unsigned int*)alloc(4096 + 256); // 16 batches x 64 dwords + det flag
  int*            dflag  = (int*)(flags + 1024);

  hipMemsetAsync(flags, 0, 4096 + 256, stream);   // zero flags + detection flag each call

  detect_i64<<<dim3(1), dim3(256), 0, stream>>>(ids, dflag);
  convert_bf16<<<dim3((H * H) / 1024), dim3(256), 0, stream>>>(w_hx, whx_bf, H * H);
  convert_bf16<<<dim3((H * H) / 1024), dim3(256), 0, stream>>>(w_hh, whh_bf, H * H);
  convert_bf16<<<dim3((V * H) / 1024), dim3(256), 0, stream>>>(w_yh, wyh_bf, V * H);
  gather_embed<<<dim3(BS), dim3(256), 0, stream>>>(ids, emb, x_bf, dflag);

  // xin = x @ w_hx^T : M=4096, N=1024, K=1024 -> 256 WGs
  gemm_bt<<<dim3((BS / 128) * (H / 128)), dim3(256), 0, stream>>>(x_bf, whx_bf, xin, BS, H, H);

  // sequential recurrence (persistent, per-batch flag sync)
  rnn_step_all<<<dim3(256), dim3(1024), 0, stream>>>(xin, whh_bf, hs, hs_bf, flags);

  // logits = hs @ w_yh^T : M=4096, N=32000, K=1024 -> 8000 WGs
  gemm_bt<<<dim3((BS / 128) * (V / 128)), dim3(256), 0, stream>>>(hs_bf, wyh_bf, out, BS, V, H);
}

// Round 3
// 931.899 us; speedup vs baseline: 5.7519x; 1.1481x over previous
//
#include <hip/hip_runtime.h>
#include <stdint.h>

typedef __attribute__((ext_vector_type(8)))  short   short8;
typedef __attribute__((ext_vector_type(8)))  unsigned short ushort8;
typedef __attribute__((ext_vector_type(8)))  __bf16  bf16x8;
typedef __attribute__((ext_vector_type(4)))  float   floatx4;
typedef __attribute__((ext_vector_type(4)))  unsigned short ushort4v;

#define AS1 __attribute__((address_space(1)))
#define AS3 __attribute__((address_space(3)))

__device__ __forceinline__ unsigned short f2bf(float f) {
  unsigned u = __builtin_bit_cast(unsigned, f);
  u = (u + 0x7FFFu + ((u >> 16) & 1u)) >> 16;   // RNE
  return (unsigned short)u;
}
__device__ __forceinline__ float bf2f(unsigned short h) {
  unsigned u = ((unsigned)h) << 16;
  return __builtin_bit_cast(float, u);
}

// ---------------- f32 -> bf16 convert (n multiple of 1024) ----------------
__global__ __launch_bounds__(256) void convert_bf16(const float* __restrict__ src,
                                                    unsigned short* __restrict__ dst,
                                                    int n) {
  int i = (blockIdx.x * 256 + threadIdx.x) * 4;
  if (i >= n) return;
  float4 v = *(const float4*)(src + i);
  ushort4v o;
  o.x = f2bf(v.x); o.y = f2bf(v.y); o.z = f2bf(v.z); o.w = f2bf(v.w);
  *(ushort4v*)(dst + i) = o;
}

// ---------------- int64-vs-int32 id layout detection ----------------
__global__ __launch_bounds__(256) void detect_i64(const int* __restrict__ idbuf,
                                                  int* __restrict__ flag) {
  int v = 0;
  for (int i = threadIdx.x; i < 2048; i += 256) v |= idbuf[2 * i + 1];
  if (v != 0) atomicOr(flag, 1);
}

// ---------------- gather rows of emb -> bf16 x ----------------
__global__ __launch_bounds__(256) void gather_embed(const int* __restrict__ ids,
                                                    const float* __restrict__ emb,
                                                    unsigned short* __restrict__ xbf,
                                                    const int* __restrict__ flag) {
  int i = blockIdx.x;                      // 0..4095 (b*256+s)
  int row = (*flag != 0) ? ids[i] : ids[2 * i];   // int32 vs int64 layout
  const float* src = emb + (size_t)row * 1024 + threadIdx.x * 4;
  float4 v = *(const float4*)src;
  ushort4v o;
  o.x = f2bf(v.x); o.y = f2bf(v.y); o.z = f2bf(v.z); o.w = f2bf(v.w);
  *(ushort4v*)(xbf + (size_t)i * 1024 + threadIdx.x * 4) = o;
}

// ---------------- bf16 GEMM  C[M,N] = A[M,K] * B[N,K]^T  (f32 out) ----------------
__global__ __launch_bounds__(256) void gemm_bt(const unsigned short* __restrict__ A,
                                               const unsigned short* __restrict__ B,
                                               float* __restrict__ C,
                                               int M, int N, int K) {
  __shared__ unsigned short lA[128 * 64];
  __shared__ unsigned short lB[128 * 64];
  const int nwg  = gridDim.x;
  const int wgid = blockIdx.x;
  const int q    = nwg >> 3;                       // XCD-aware swizzle (nwg % 8 == 0)
  const int swz  = (wgid & 7) * q + (wgid >> 3);
  const int ntx  = N >> 7;
  const int bx   = swz % ntx;
  const int by   = swz / ntx;
  const int tid  = threadIdx.x;
  const int lane = tid & 63;
  const int w    = tid >> 6;
  const int wr   = w >> 1, wc = w & 1;

  floatx4 acc[4][4];
#pragma unroll
  for (int m = 0; m < 4; ++m)
#pragma unroll
    for (int n = 0; n < 4; ++n) acc[m][n] = (floatx4){0.f, 0.f, 0.f, 0.f};

  const size_t rowA0 = (size_t)by * 128;
  const size_t colB0 = (size_t)bx * 128;

  for (int k0 = 0; k0 < K; k0 += 64) {
#pragma unroll
    for (int p = 0; p < 4; ++p) {
      int cc = p * 256 + tid;       // 16B chunk id, 0..1023
      int r  = cc >> 3;             // tile row 0..127
      int c8 = cc & 7;              // 16B chunk within row
      const unsigned short* srcA = A + (rowA0 + r) * K + k0 + c8 * 8;
      const unsigned short* srcB = B + (colB0 + r) * K + k0 + c8 * 8;
      __builtin_amdgcn_global_load_lds((const AS1 unsigned int*)srcA,
                                       (AS3 unsigned int*)&lA[cc * 8], 16, 0, 0);
      __builtin_amdgcn_global_load_lds((const AS1 unsigned int*)srcB,
                                       (AS3 unsigned int*)&lB[cc * 8], 16, 0, 0);
    }
    __syncthreads();
#pragma unroll
    for (int kk = 0; kk < 2; ++kk) {
      const int kofs = kk * 32 + (lane >> 4) * 8;
      bf16x8 af[4], bfv[4];
#pragma unroll
      for (int m = 0; m < 4; ++m) {
        int r = wr * 64 + m * 16 + (lane & 15);
        af[m] = *(const bf16x8*)&lA[r * 64 + kofs];
      }
#pragma unroll
      for (int n = 0; n < 4; ++n) {
        int r = wc * 64 + n * 16 + (lane & 15);
        bfv[n] = *(const bf16x8*)&lB[r * 64 + kofs];
      }
#pragma unroll
      for (int m = 0; m < 4; ++m)
#pragma unroll
        for (int n = 0; n < 4; ++n)
          acc[m][n] = __builtin_amdgcn_mfma_f32_16x16x32_bf16(af[m], bfv[n], acc[m][n], 0, 0, 0);
    }
    __syncthreads();
  }

#pragma unroll
  for (int m = 0; m < 4; ++m) {
#pragma unroll
    for (int j = 0; j < 4; ++j) {
      size_t row = rowA0 + wr * 64 + m * 16 + ((lane >> 4) * 4 + j);
      float* crow = C + row * (size_t)N + colB0 + wc * 64 + (lane & 15);
#pragma unroll
      for (int n = 0; n < 4; ++n) crow[n * 16] = acc[m][n][j];
    }
  }
}

// ---------------- recurrence: h_t = tanh(xin_t + h_{t-1} @ w_hh^T) ----------------
// 256 WGs = 16 batches x 16 slices of 64 output rows. 1024 threads/WG, 1 WG/CU.
// Thread (o=tid&63, kc=tid>>6) holds w_hh[slice*64+o][kc*64 .. +64) as f32 in regs
// (forced resident via opaque asm). Sync: data-as-flag — hs pre-filled with NaN,
// each (t,slot) written exactly once with device-coherent stores; consumers poll
// the data itself and retry while any lane sees NaN. No flags, no drains.
__global__ __launch_bounds__(1024, 4) void rnn_step_all(const float* __restrict__ xin,
                                                        const unsigned short* __restrict__ whh_bf,
                                                        float* __restrict__ hs,
                                                        unsigned short* __restrict__ hs_bf) {
  const int b     = blockIdx.x >> 4;
  const int slice = blockIdx.x & 15;
  const int tid   = threadIdx.x;
  const int o     = tid & 63;     // lane within wave
  const int kc    = tid >> 6;     // wave id == k-chunk == source slice

  __shared__ __align__(16) float hl[1024];    // wave-private regions, no barrier
  __shared__ float red[2][1024];              // double-buffered -> one barrier/step

  float wf[64];
  {
    const unsigned short* wrow = whh_bf + (size_t)(slice * 64 + o) * 1024 + kc * 64;
#pragma unroll
    for (int j = 0; j < 8; ++j) {
      ushort8 wv = *(const ushort8*)(wrow + j * 8);
#pragma unroll
      for (int e = 0; e < 8; ++e) wf[j * 8 + e] = bf2f(wv[e]);
    }
    // Force the 64 weight values to stay materialized in registers: without
    // this the compiler rematerializes the loads+converts inside the t-loop
    // (VGPR_Count=48 in round 1 proved it).
#pragma unroll
    for (int j = 0; j < 64; ++j) asm volatile("" : "+v"(wf[j]));
  }

  const size_t bbase = (size_t)b * 256 * 1024;

  for (int t = 0; t < 256; ++t) {
    float s = 0.0f;
    if (tid < 64) s = xin[bbase + (size_t)t * 1024 + slice * 64 + tid];  // prefetch

    if (t == 0) {
      hl[tid] = 0.0f;
    } else {
      // wave kc polls its own 64 h-values (written once, NaN until then)
      const float* src = &hs[bbase + (size_t)(t - 1) * 1024 + (size_t)kc * 64 + o];
      float v;
      do {
        v = __hip_atomic_load(src, __ATOMIC_RELAXED, __HIP_MEMORY_SCOPE_AGENT);
      } while (__any(v != v));
      hl[tid] = v;                    // wave-private region; lgkmcnt orders r-a-w
    }

    float sum = 0.0f;
#pragma unroll
    for (int j4 = 0; j4 < 16; ++j4) {
      float4 hv = *(const float4*)&hl[kc * 64 + j4 * 4];   // all-lane broadcast
      sum += wf[j4 * 4 + 0] * hv.x + wf[j4 * 4 + 1] * hv.y +
             wf[j4 * 4 + 2] * hv.z + wf[j4 * 4 + 3] * hv.w;
    }
    red[t & 1][tid] = sum;
    __syncthreads();                  // red ready (the only barrier per step)

    if (tid < 64) {
#pragma unroll
      for (int k2 = 0; k2 < 16; ++k2) s += red[t & 1][k2 * 64 + tid];
      // fast tanh: 1 - 2/(e^{2s}+1); exact at saturation, ample precision here
      float e  = __expf(2.0f * s);
      float hv = 1.0f - 2.0f * __builtin_amdgcn_rcpf(e + 1.0f);
      size_t idx = bbase + (size_t)t * 1024 + (size_t)slice * 64 + tid;
      __hip_atomic_store(&hs[idx], hv, __ATOMIC_RELAXED, __HIP_MEMORY_SCOPE_AGENT);
      hs_bf[idx] = f2bf(hv);          // plain store; consumed after kernel end
    }
  }
}

// ---------------- host launch ----------------
extern "C" void kernel_launch(void* const* d_in, const int* in_sizes, int n_in,
                              void* d_out, int out_size, void* d_ws, size_t ws_size,
                              hipStream_t stream) {
  const int*   ids  = (const int*)d_in[0];     // [16,256]
  const float* emb  = (const float*)d_in[1];   // [32000,1024]
  const float* w_hx = (const float*)d_in[2];   // [1024,1024]
  const float* w_hh = (const float*)d_in[3];   // [1024,1024]
  const float* w_yh = (const float*)d_in[4];   // [32000,1024]
  float*       out  = (float*)d_out;           // [16,256,32000]

  const int B = 16, S = 256, H = 1024, V = 32000;
  const int BS = B * S;

  char*  ws  = (char*)d_ws;
  size_t off = 0;
  auto alloc = [&](size_t bytes) {
    size_t cur = off;
    off += (bytes + 255) & ~(size_t)255;
    return (void*)(ws + cur);
  };

  unsigned short* whx_bf = (unsigned short*)alloc((size_t)H * H * 2);
  unsigned short* whh_bf = (unsigned short*)alloc((size_t)H * H * 2);
  unsigned short* wyh_bf = (unsigned short*)alloc((size_t)V * H * 2);
  unsigned short* x_bf   = (unsigned short*)alloc((size_t)BS * H * 2);
  float*          xin    = (float*)alloc((size_t)BS * H * 4);
  float*          hs     = (float*)alloc((size_t)BS * H * 4);
  unsigned short* hs_bf  = (unsigned short*)alloc((size_t)BS * H * 2);
  int*            dflag  = (int*)alloc(256);

  // Re-arm the NaN sentinel every call (replays would otherwise see stale
  // non-NaN h values and race ahead). 0xFF bytes -> every f32 is NaN.
  hipMemsetAsync(hs, 0xFF, (size_t)BS * H * 4, stream);
  hipMemsetAsync(dflag, 0, 256, stream);

  detect_i64<<<dim3(1), dim3(256), 0, stream>>>(ids, dflag);
  convert_bf16<<<dim3((H * H) / 1024), dim3(256), 0, stream>>>(w_hx, whx_bf, H * H);
  convert_bf16<<<dim3((H * H) / 1024), dim3(256), 0, stream>>>(w_hh, whh_bf, H * H);
  convert_bf16<<<dim3((V * H) / 1024), dim3(256), 0, stream>>>(w_yh, wyh_bf, V * H);
  gather_embed<<<dim3(BS), dim3(256), 0, stream>>>(ids, emb, x_bf, dflag);

  // xin = x @ w_hx^T : M=4096, N=1024, K=1024 -> 256 WGs
  gemm_bt<<<dim3((BS / 128) * (H / 128)), dim3(256), 0, stream>>>(x_bf, whx_bf, xin, BS, H, H);

  // sequential recurrence (persistent, data-as-flag sync)
  rnn_step_all<<<dim3(256), dim3(1024), 0, stream>>>(xin, whh_bf, hs, hs_bf);

  // logits = hs @ w_yh^T : M=4096, N=32000, K=1024 -> 8000 WGs
  gemm_bt<<<dim3((BS / 128) * (V / 128)), dim3(256), 0, stream>>>(hs_bf, wyh_bf, out, BS, V, H);
}